// Round 17
// baseline (1195.225 us; speedup 1.0000x reference)
//
#include <hip/hip_runtime.h>
#include <hip/hip_fp16.h>
#include <hip/hip_cooperative_groups.h>

namespace cg = cooperative_groups;

#define B_ 64
#define N_ 4096
#define C_ 10
#define D_ 8
#define E_ 16
#define EPS_ 1e-7f
#define NT_ 4
#define NBLK_ (N_ / NT_)          // 1024 pass blocks
#define NSLOT_ NBLK_              // 1024 partial slots (1 per block)
#define PROW_ 80                  // u32 per partial row (160 halfs)
#define NSG_ 8                    // fallback reduce stage-A slot groups

typedef _Float16 h2_t __attribute__((ext_vector_type(2)));
typedef __fp16   p2_t __attribute__((ext_vector_type(2)));   // cvt_pkrtz ret type

__device__ inline unsigned pkh(float a, float b) {   // f32x2 -> packed fp16
    p2_t t = __builtin_amdgcn_cvt_pkrtz(a, b);
    return *(unsigned*)&t;
}
#if __has_builtin(__builtin_amdgcn_fdot2)
__device__ inline float fd2(unsigned a, unsigned b, float c) {
    h2_t av = *(h2_t*)&a, bv = *(h2_t*)&b;
    return __builtin_amdgcn_fdot2(av, bv, c, false);
}
#else
__device__ inline float fd2(unsigned a, unsigned b, float c) {
    h2_t av = *(h2_t*)&a, bv = *(h2_t*)&b;
    return fmaf((float)av.x, (float)bv.x, fmaf((float)av.y, (float)bv.y, c));
}
#endif
__device__ inline float hlo(unsigned u) { h2_t t = *(h2_t*)&u; return (float)t.x; }
__device__ inline float hhi(unsigned u) { h2_t t = *(h2_t*)&u; return (float)t.y; }
__device__ inline unsigned hpack(float a, float b) {
    __half2 t = __floats2half2_rn(a, b);
    return *(unsigned*)&t;
}
__device__ inline float2 hunpack(unsigned u) {
    return __half22float2(*(const __half2*)&u);
}

// ---- shared staging: W -> fp16 d-pair granules [n][c][d2][eq], x -> words ----
__device__ __forceinline__ void stage_wx(
    uint4* wlds, unsigned* xlds, const float* __restrict__ x,
    const float* __restrict__ W, int tid, int blk)
{
    const int n0 = blk * NT_;
    const float4* wg = (const float4*)W + (size_t)blk * (NT_ * 320);
#pragma unroll
    for (int k = 0; k < 3; ++k) {
        const int g = k * 256 + tid;          // [0, 640)
        if (g < NT_ * C_ * 16) {
            const int n   = g / 160;
            const int rem = g - n * 160;
            const int c   = rem >> 4;
            const int r2  = rem & 15;
            const int d2  = r2 >> 2;
            const int eqs = r2 & 3;
            const float4 g0 = wg[n * 320 + c * 32 + (2 * d2) * 4 + eqs];
            const float4 g1 = wg[n * 320 + c * 32 + (2 * d2 + 1) * 4 + eqs];
            wlds[((n * C_ + c) * 4 + d2) * 4 + eqs] =
                make_uint4(pkh(g0.x, g1.x), pkh(g0.y, g1.y),
                           pkh(g0.z, g1.z), pkh(g0.w, g1.w));
        }
    }
    const float4* xg = (const float4*)x;
#pragma unroll
    for (int k = 0; k < 2; ++k) {
        const int g = k * 256 + tid;          // [0, 512)
        const int b = g >> 3;
        const int r = g & 7;
        const int n = r >> 1;
        const int dq = r & 1;
        const float4 v = xg[((size_t)b * N_ + n0 + n) * 2 + dq];
        *(uint2*)&xlds[(n * B_ + b) * 4 + dq * 2] =
            make_uint2(pkh(v.x, v.y), pkh(v.z, v.w));
    }
}

// ---- one routing pass over this block's NT n (post-staging) ----
template <bool UNIFORM>
__device__ __forceinline__ void pass_phase(
    const uint4* wlds, const unsigned* xlds, float (*xch)[2][2][16][2],
    int tid, int blk, const float* __restrict__ v_cum,
    unsigned* __restrict__ partial)
{
    const int wv   = tid >> 6;
    const int lane = tid & 63;
    const int eq   = lane & 3;
    const int bl   = lane >> 2;
    const int h    = wv & 1;
    const int cg_  = wv >> 1;          // c-group: 0 -> c 0..4, 1 -> c 5..9
    const int b0   = h * 32 + bl;
    const int b1   = b0 + 16;
    const int cbase = cg_ * 5;

    unsigned vcp0[5][2], vcp1[5][2];
    if (!UNIFORM) {
#pragma unroll
        for (int cc = 0; cc < 5; ++cc) {
            const int c = cbase + cc;
            const float4 a = *(const float4*)(v_cum + (b0 * C_ + c) * E_ + eq * 4);
            vcp0[cc][0] = pkh(a.x, a.y); vcp0[cc][1] = pkh(a.z, a.w);
            const float4 d = *(const float4*)(v_cum + (b1 * C_ + c) * E_ + eq * 4);
            vcp1[cc][0] = pkh(d.x, d.y); vcp1[cc][1] = pkh(d.z, d.w);
        }
    }

    float4 acc0[5], acc1[5];
#pragma unroll
    for (int cc = 0; cc < 5; ++cc) {
        acc0[cc] = make_float4(0.f, 0.f, 0.f, 0.f);
        acc1[cc] = make_float4(0.f, 0.f, 0.f, 0.f);
    }

#pragma unroll 1
    for (int j = 0; j < NT_; ++j) {
        const uint4 xq0 = *(const uint4*)&xlds[(j * B_ + b0) * 4];
        const uint4 xq1 = *(const uint4*)&xlds[(j * B_ + b1) * 4];
        const unsigned xa[4] = {xq0.x, xq0.y, xq0.z, xq0.w};
        const unsigned xb[4] = {xq1.x, xq1.y, xq1.z, xq1.w};

        if (UNIFORM) {
#pragma unroll
            for (int cc = 0; cc < 5; ++cc) {
                const uint4* wq = &wlds[(j * C_ + cbase + cc) * 16];
#pragma unroll
                for (int d2 = 0; d2 < 4; ++d2) {
                    const uint4 q = wq[d2 * 4 + eq];
                    acc0[cc].x = fd2(xa[d2], q.x, acc0[cc].x);
                    acc0[cc].y = fd2(xa[d2], q.y, acc0[cc].y);
                    acc0[cc].z = fd2(xa[d2], q.z, acc0[cc].z);
                    acc0[cc].w = fd2(xa[d2], q.w, acc0[cc].w);
                    acc1[cc].x = fd2(xb[d2], q.x, acc1[cc].x);
                    acc1[cc].y = fd2(xb[d2], q.y, acc1[cc].y);
                    acc1[cc].z = fd2(xb[d2], q.z, acc1[cc].z);
                    acc1[cc].w = fd2(xb[d2], q.w, acc1[cc].w);
                }
            }
        } else {
            unsigned uhp0[5][2], uhp1[5][2];
            float wgt0[5], wgt1[5];
            float s0 = 0.f, s1 = 0.f;
#pragma unroll
            for (int cc = 0; cc < 5; ++cc) {
                const uint4* wq = &wlds[(j * C_ + cbase + cc) * 16];
                float4 u0 = make_float4(0.f, 0.f, 0.f, 0.f);
                float4 u1 = make_float4(0.f, 0.f, 0.f, 0.f);
#pragma unroll
                for (int d2 = 0; d2 < 4; ++d2) {
                    const uint4 q = wq[d2 * 4 + eq];
                    u0.x = fd2(xa[d2], q.x, u0.x);
                    u0.y = fd2(xa[d2], q.y, u0.y);
                    u0.z = fd2(xa[d2], q.z, u0.z);
                    u0.w = fd2(xa[d2], q.w, u0.w);
                    u1.x = fd2(xb[d2], q.x, u1.x);
                    u1.y = fd2(xb[d2], q.y, u1.y);
                    u1.z = fd2(xb[d2], q.z, u1.z);
                    u1.w = fd2(xb[d2], q.w, u1.w);
                }
                const unsigned up00 = pkh(u0.x, u0.y), up01 = pkh(u0.z, u0.w);
                const unsigned up10 = pkh(u1.x, u1.y), up11 = pkh(u1.z, u1.w);
                float t0 = fd2(up00, vcp0[cc][0], fd2(up01, vcp0[cc][1], 0.f));
                t0 += __shfl_xor(t0, 1); t0 += __shfl_xor(t0, 2);
                float t1 = fd2(up10, vcp1[cc][0], fd2(up11, vcp1[cc][1], 0.f));
                t1 += __shfl_xor(t1, 1); t1 += __shfl_xor(t1, 2);
                wgt0[cc] = __expf(t0); s0 += wgt0[cc];
                wgt1[cc] = __expf(t1); s1 += wgt1[cc];
                uhp0[cc][0] = up00; uhp0[cc][1] = up01;
                uhp1[cc][0] = up10; uhp1[cc][1] = up11;
            }
            if (eq == 0) {
                xch[j & 1][cg_][h][bl][0] = s0;
                xch[j & 1][cg_][h][bl][1] = s1;
            }
            __syncthreads();
            const float i0 = 1.f / (s0 + xch[j & 1][cg_ ^ 1][h][bl][0]);
            const float i1 = 1.f / (s1 + xch[j & 1][cg_ ^ 1][h][bl][1]);
#pragma unroll
            for (int cc = 0; cc < 5; ++cc) {
                const float g0 = wgt0[cc] * i0, g1 = wgt1[cc] * i1;
                acc0[cc].x = fmaf(g0, hlo(uhp0[cc][0]), acc0[cc].x);
                acc0[cc].y = fmaf(g0, hhi(uhp0[cc][0]), acc0[cc].y);
                acc0[cc].z = fmaf(g0, hlo(uhp0[cc][1]), acc0[cc].z);
                acc0[cc].w = fmaf(g0, hhi(uhp0[cc][1]), acc0[cc].w);
                acc1[cc].x = fmaf(g1, hlo(uhp1[cc][0]), acc1[cc].x);
                acc1[cc].y = fmaf(g1, hhi(uhp1[cc][0]), acc1[cc].y);
                acc1[cc].z = fmaf(g1, hlo(uhp1[cc][1]), acc1[cc].z);
                acc1[cc].w = fmaf(g1, hhi(uhp1[cc][1]), acc1[cc].w);
            }
        }
    }

    const float fold = UNIFORM ? 0.1f : 1.f;   // softmax(0) = 1/10 folded out
#pragma unroll
    for (int cc = 0; cc < 5; ++cc) {
        const int c = cbase + cc;
        *(uint2*)(partial + ((size_t)b0 * NSLOT_ + blk) * PROW_ + c * 8 + eq * 2) =
            make_uint2(hpack(acc0[cc].x * fold, acc0[cc].y * fold),
                       hpack(acc0[cc].z * fold, acc0[cc].w * fold));
        *(uint2*)(partial + ((size_t)b1 * NSLOT_ + blk) * PROW_ + c * 8 + eq * 2) =
            make_uint2(hpack(acc1[cc].x * fold, acc1[cc].y * fold),
                       hpack(acc1[cc].z * fold, acc1[cc].w * fold));
    }
}

// ===================== fused cooperative kernel =====================
// 1024 blocks x 256 thr, all co-resident (20.5 KB LDS, <=128 VGPR).
// Stage W/x ONCE; 3 routing iterations with 2 grid.syncs each (5 total).
// Reduce: blocks 0..63 (one per b) sum all 1024 slots in-block, squash,
// update v_cum (t<2) or write out (t=2).
__global__ __launch_bounds__(256, 4) void caps_fused(
    const float* __restrict__ x, const float* __restrict__ W,
    unsigned* __restrict__ partial, float* __restrict__ v_cum,
    float* __restrict__ out)
{
    __shared__ uint4    wlds[NT_ * C_ * 16];    // 10240 B
    __shared__ unsigned xlds[NT_ * B_ * 4];     // 4096 B
    __shared__ float    xch[2][2][2][16][2];    // 1024 B
    __shared__ float    red[8][20][8];          // 5120 B

    const int tid = (int)threadIdx.x;
    const int blk = (int)blockIdx.x;

    stage_wx(wlds, xlds, x, W, tid, blk);
    __syncthreads();

    cg::grid_group grid = cg::this_grid();

#pragma unroll 1
    for (int t = 0; t < 3; ++t) {
        if (t == 0) pass_phase<true >(wlds, xlds, xch, tid, blk, v_cum, partial);
        else        pass_phase<false>(wlds, xlds, xch, tid, blk, v_cum, partial);

        __threadfence();
        grid.sync();

        if (blk < B_) {
            const int b = blk;
            const int sc   = tid >> 5;          // 0..7 (chunks of 128 slots)
            const int col4 = tid & 31;          // active < 20
            if (col4 < 20) {
                float s[8];
#pragma unroll
                for (int p = 0; p < 8; ++p) s[p] = 0.f;
                const uint4* base = (const uint4*)(partial +
                    ((size_t)b * NSLOT_ + sc * 128) * PROW_) + col4;
#pragma unroll 4
                for (int k = 0; k < 128; ++k) {
                    const uint4 q = base[k * (PROW_ / 4)];
                    const float2 f0 = hunpack(q.x), f1 = hunpack(q.y);
                    const float2 f2 = hunpack(q.z), f3 = hunpack(q.w);
                    s[0] += f0.x; s[1] += f0.y; s[2] += f1.x; s[3] += f1.y;
                    s[4] += f2.x; s[5] += f2.y; s[6] += f3.x; s[7] += f3.y;
                }
#pragma unroll
                for (int p = 0; p < 8; ++p) red[sc][col4][p] = s[p];
            }
            __syncthreads();
            if (tid < C_ * E_) {
                float s = 0.f;
#pragma unroll
                for (int ch = 0; ch < 8; ++ch) s += red[ch][tid >> 3][tid & 7];
                float p = s * s;                 // sum over 16 e-lanes of c
                p += __shfl_xor(p, 1); p += __shfl_xor(p, 2);
                p += __shfl_xor(p, 4); p += __shfl_xor(p, 8);
                const float sq = (p / (1.f + p)) * rsqrtf(p + EPS_);
                const float v = sq * s;
                const int o = b * (C_ * E_) + tid;
                if (t == 2)      out[o] = v;
                else if (t == 0) v_cum[o] = v;
                else             v_cum[o] += v;
            }
            __syncthreads();
        }

        if (t < 2) {
            __threadfence();
            grid.sync();
        }
    }
}

// ===================== fallback path (proven R16) =====================
template <bool UNIFORM>
__global__ __launch_bounds__(256, 4) void caps_pass(
    const float* __restrict__ x, const float* __restrict__ W,
    const float* __restrict__ v_cum, unsigned* __restrict__ partial)
{
    __shared__ uint4    wlds[NT_ * C_ * 16];
    __shared__ unsigned xlds[NT_ * B_ * 4];
    __shared__ float    xch[2][2][2][16][2];
    const int tid = (int)threadIdx.x;
    const int blk = (int)blockIdx.x;
    stage_wx(wlds, xlds, x, W, tid, blk);
    __syncthreads();
    pass_phase<UNIFORM>(wlds, xlds, xch, tid, blk, v_cum, partial);
}

__global__ __launch_bounds__(256) void caps_redA(
    const unsigned* __restrict__ partial, float* __restrict__ sub)
{
    const int b  = (int)blockIdx.x >> 3;
    const int sg = (int)blockIdx.x & 7;
    const int tid = (int)threadIdx.x;
    const int sc   = tid >> 5;
    const int col4 = tid & 31;
    __shared__ float red[8][20][8];
    if (col4 < 20) {
        float s[8];
#pragma unroll
        for (int p = 0; p < 8; ++p) s[p] = 0.f;
        const int slot0 = sg * (NSLOT_ / NSG_) + sc * 16;
        const uint4* base = (const uint4*)(partial +
            ((size_t)b * NSLOT_ + slot0) * PROW_) + col4;
#pragma unroll 4
        for (int k = 0; k < 16; ++k) {
            const uint4 q = base[k * (PROW_ / 4)];
            const float2 f0 = hunpack(q.x), f1 = hunpack(q.y);
            const float2 f2 = hunpack(q.z), f3 = hunpack(q.w);
            s[0] += f0.x; s[1] += f0.y; s[2] += f1.x; s[3] += f1.y;
            s[4] += f2.x; s[5] += f2.y; s[6] += f3.x; s[7] += f3.y;
        }
#pragma unroll
        for (int p = 0; p < 8; ++p) red[sc][col4][p] = s[p];
    }
    __syncthreads();
    if (tid < 160) {
        const int c4 = tid >> 3, p = tid & 7;
        float s = 0.f;
#pragma unroll
        for (int ch = 0; ch < 8; ++ch) s += red[ch][c4][p];
        sub[((size_t)b * NSG_ + sg) * (C_ * E_) + c4 * 8 + p] = s;
    }
}

__global__ __launch_bounds__(192) void caps_redB(
    const float* __restrict__ sub, float* __restrict__ v_cum,
    float* __restrict__ out, int mode)
{
    const int b = (int)blockIdx.x;
    const int tid = (int)threadIdx.x;
    if (tid >= C_ * E_) return;
    float s = 0.f;
#pragma unroll
    for (int sg = 0; sg < NSG_; ++sg)
        s += sub[((size_t)b * NSG_ + sg) * (C_ * E_) + tid];
    float p = s * s;
    p += __shfl_xor(p, 1); p += __shfl_xor(p, 2);
    p += __shfl_xor(p, 4); p += __shfl_xor(p, 8);
    const float sc = (p / (1.f + p)) * rsqrtf(p + EPS_);
    const float v = sc * s;
    const int o = b * (C_ * E_) + tid;
    if (mode == 2)      out[o] = v;
    else if (mode == 0) v_cum[o] = v;
    else                v_cum[o] += v;
}

extern "C" void kernel_launch(void* const* d_in, const int* in_sizes, int n_in,
                              void* d_out, int out_size, void* d_ws, size_t ws_size,
                              hipStream_t stream) {
    const float* x = (const float*)d_in[0];
    const float* W = (const float*)d_in[1];
    float* out = (float*)d_out;

    unsigned* partial = (unsigned*)d_ws;   // 64*1024*80*4 = 20.97 MB
    float* sub = (float*)((char*)d_ws +
        (size_t)B_ * NSLOT_ * PROW_ * sizeof(unsigned));          // 327 KB
    float* v_cum = sub + (size_t)B_ * NSG_ * C_ * E_;             // 40 KB

    void* args[5];
    args[0] = (void*)&x;
    args[1] = (void*)&W;
    args[2] = (void*)&partial;
    args[3] = (void*)&v_cum;
    args[4] = (void*)&out;
    hipError_t err = hipLaunchCooperativeKernel((void*)caps_fused,
                                                dim3(NBLK_), dim3(256),
                                                args, 0, stream);
    if (err != hipSuccess) {
        (void)hipGetLastError();   // clear sticky error, use proven path
        for (int t = 0; t < 3; ++t) {
            if (t == 0)
                caps_pass<true ><<<dim3(NBLK_), 256, 0, stream>>>(x, W, v_cum, partial);
            else
                caps_pass<false><<<dim3(NBLK_), 256, 0, stream>>>(x, W, v_cum, partial);
            caps_redA<<<dim3(B_ * NSG_), 256, 0, stream>>>(partial, sub);
            caps_redB<<<dim3(B_), 192, 0, stream>>>(sub, v_cum, out, t);
        }
    }
}

// Round 18
// 94.368 us; speedup vs baseline: 12.6655x; 12.6655x over previous
//
#include <hip/hip_runtime.h>
#include <hip/hip_fp16.h>

#define B_ 64
#define N_ 4096
#define C_ 10
#define D_ 8
#define E_ 16
#define EPS_ 1e-7f
#define NT_ 4
#define NBLK_ (N_ / NT_)          // 1024 pass blocks
#define NSLOT_ NBLK_              // 1024 partial slots (1 per block)
#define PROW_ 80                  // u32 per partial row (160 halfs)
#define NSG_ 8                    // reduce stage-A slot groups
#define WG_ (NT_ * C_ * 16)       // 640 W granules per block
#define XG_ (NT_ * B_)            // 256 x uint4 per block

typedef _Float16 h2_t __attribute__((ext_vector_type(2)));
typedef __fp16   p2_t __attribute__((ext_vector_type(2)));   // cvt_pkrtz ret type

__device__ inline unsigned pkh(float a, float b) {   // f32x2 -> packed fp16
    p2_t t = __builtin_amdgcn_cvt_pkrtz(a, b);
    return *(unsigned*)&t;
}
#if __has_builtin(__builtin_amdgcn_fdot2)
__device__ inline float fd2(unsigned a, unsigned b, float c) {
    h2_t av = *(h2_t*)&a, bv = *(h2_t*)&b;
    return __builtin_amdgcn_fdot2(av, bv, c, false);
}
#else
__device__ inline float fd2(unsigned a, unsigned b, float c) {
    h2_t av = *(h2_t*)&a, bv = *(h2_t*)&b;
    return fmaf((float)av.x, (float)bv.x, fmaf((float)av.y, (float)bv.y, c));
}
#endif
__device__ inline float hlo(unsigned u) { h2_t t = *(h2_t*)&u; return (float)t.x; }
__device__ inline float hhi(unsigned u) { h2_t t = *(h2_t*)&u; return (float)t.y; }
__device__ inline unsigned hpack(float a, float b) {
    __half2 t = __floats2half2_rn(a, b);
    return *(unsigned*)&t;
}
__device__ inline float2 hunpack(unsigned u) {
    return __half22float2(*(const __half2*)&u);
}

// Block: 256 thr = 4 waves = (h: b-half) x (cg: c-half, 5 classes each).
// Thread owns TWO b (b0=h*32+bl, b1=b0+16) and FIVE c; fp16 d-pair data,
// v_dot2_f32_f16 contraction. PACK (t=0): convert fp32 W/x -> LDS granules
// AND stream them to wpk/xpk for later passes. LOAD (t>0): direct uint4 copy.
template <bool UNIFORM>
__global__ __launch_bounds__(256, 4) void caps_pass(
    const float* __restrict__ x, const float* __restrict__ W,
    const float* __restrict__ v_cum, unsigned* __restrict__ partial,
    uint4* __restrict__ wpk, uint4* __restrict__ xpk)
{
    __shared__ uint4    wlds[WG_];              // 10240 B
    __shared__ unsigned xlds[XG_ * 4];          // 4096 B
    __shared__ float    xch[2][2][2][16][2];    // 1024 B

    const int tid = (int)threadIdx.x;
    const int blk = (int)blockIdx.x;
    const int n0  = blk * NT_;

    if (UNIFORM) {
        // ---- pack W fp32 -> fp16 granules; store to LDS + wpk ----
        const float4* wg = (const float4*)W + (size_t)blk * (NT_ * 320);
#pragma unroll
        for (int k = 0; k < 3; ++k) {
            const int g = k * 256 + tid;          // [0, 640)
            if (g < WG_) {
                const int n   = g / 160;
                const int rem = g - n * 160;
                const int c   = rem >> 4;
                const int r2  = rem & 15;
                const int d2  = r2 >> 2;
                const int eqs = r2 & 3;
                const float4 g0 = wg[n * 320 + c * 32 + (2 * d2) * 4 + eqs];
                const float4 g1 = wg[n * 320 + c * 32 + (2 * d2 + 1) * 4 + eqs];
                const uint4 q = make_uint4(pkh(g0.x, g1.x), pkh(g0.y, g1.y),
                                           pkh(g0.z, g1.z), pkh(g0.w, g1.w));
                wlds[g] = q;
                wpk[(size_t)blk * WG_ + g] = q;
            }
        }
        // ---- pack x -> LDS words + xpk ----
        const float4* xg = (const float4*)x;
#pragma unroll
        for (int k = 0; k < 2; ++k) {
            const int g = k * 256 + tid;          // [0, 512)
            const int b = g >> 3;
            const int r = g & 7;
            const int n = r >> 1;
            const int dq = r & 1;
            const float4 v = xg[((size_t)b * N_ + n0 + n) * 2 + dq];
            const uint2 p = make_uint2(pkh(v.x, v.y), pkh(v.z, v.w));
            *(uint2*)&xlds[(n * B_ + b) * 4 + dq * 2] = p;
            *(uint2*)((unsigned*)(xpk + (size_t)blk * XG_) + (n * B_ + b) * 4 + dq * 2) = p;
        }
    } else {
        // ---- direct staged copy from packed arrays ----
        const uint4* wsrc = wpk + (size_t)blk * WG_;
#pragma unroll
        for (int k = 0; k < 3; ++k) {
            const int g = k * 256 + tid;
            if (g < WG_) wlds[g] = wsrc[g];
        }
        const uint4* xsrc = xpk + (size_t)blk * XG_;
        if (tid < XG_) ((uint4*)xlds)[tid] = xsrc[tid];
    }
    __syncthreads();

    const int wv   = tid >> 6;
    const int lane = tid & 63;
    const int eq   = lane & 3;
    const int bl   = lane >> 2;
    const int h    = wv & 1;
    const int cg   = wv >> 1;          // c-group: 0 -> c 0..4, 1 -> c 5..9
    const int b0   = h * 32 + bl;
    const int b1   = b0 + 16;
    const int cbase = cg * 5;

    unsigned vcp0[5][2], vcp1[5][2];
    if (!UNIFORM) {
#pragma unroll
        for (int cc = 0; cc < 5; ++cc) {
            const int c = cbase + cc;
            const float4 a = *(const float4*)(v_cum + (b0 * C_ + c) * E_ + eq * 4);
            vcp0[cc][0] = pkh(a.x, a.y); vcp0[cc][1] = pkh(a.z, a.w);
            const float4 d = *(const float4*)(v_cum + (b1 * C_ + c) * E_ + eq * 4);
            vcp1[cc][0] = pkh(d.x, d.y); vcp1[cc][1] = pkh(d.z, d.w);
        }
    }

    float4 acc0[5], acc1[5];
#pragma unroll
    for (int cc = 0; cc < 5; ++cc) {
        acc0[cc] = make_float4(0.f, 0.f, 0.f, 0.f);
        acc1[cc] = make_float4(0.f, 0.f, 0.f, 0.f);
    }

#pragma unroll 1
    for (int j = 0; j < NT_; ++j) {
        const uint4 xq0 = *(const uint4*)&xlds[(j * B_ + b0) * 4];
        const uint4 xq1 = *(const uint4*)&xlds[(j * B_ + b1) * 4];
        const unsigned xa[4] = {xq0.x, xq0.y, xq0.z, xq0.w};
        const unsigned xb[4] = {xq1.x, xq1.y, xq1.z, xq1.w};

        if (UNIFORM) {
#pragma unroll
            for (int cc = 0; cc < 5; ++cc) {
                const uint4* wq = &wlds[(j * C_ + cbase + cc) * 16];
#pragma unroll
                for (int d2 = 0; d2 < 4; ++d2) {
                    const uint4 q = wq[d2 * 4 + eq];
                    acc0[cc].x = fd2(xa[d2], q.x, acc0[cc].x);
                    acc0[cc].y = fd2(xa[d2], q.y, acc0[cc].y);
                    acc0[cc].z = fd2(xa[d2], q.z, acc0[cc].z);
                    acc0[cc].w = fd2(xa[d2], q.w, acc0[cc].w);
                    acc1[cc].x = fd2(xb[d2], q.x, acc1[cc].x);
                    acc1[cc].y = fd2(xb[d2], q.y, acc1[cc].y);
                    acc1[cc].z = fd2(xb[d2], q.z, acc1[cc].z);
                    acc1[cc].w = fd2(xb[d2], q.w, acc1[cc].w);
                }
            }
        } else {
            unsigned uhp0[5][2], uhp1[5][2];
            float wgt0[5], wgt1[5];
            float s0 = 0.f, s1 = 0.f;
#pragma unroll
            for (int cc = 0; cc < 5; ++cc) {
                const uint4* wq = &wlds[(j * C_ + cbase + cc) * 16];
                float4 u0 = make_float4(0.f, 0.f, 0.f, 0.f);
                float4 u1 = make_float4(0.f, 0.f, 0.f, 0.f);
#pragma unroll
                for (int d2 = 0; d2 < 4; ++d2) {
                    const uint4 q = wq[d2 * 4 + eq];
                    u0.x = fd2(xa[d2], q.x, u0.x);
                    u0.y = fd2(xa[d2], q.y, u0.y);
                    u0.z = fd2(xa[d2], q.z, u0.z);
                    u0.w = fd2(xa[d2], q.w, u0.w);
                    u1.x = fd2(xb[d2], q.x, u1.x);
                    u1.y = fd2(xb[d2], q.y, u1.y);
                    u1.z = fd2(xb[d2], q.z, u1.z);
                    u1.w = fd2(xb[d2], q.w, u1.w);
                }
                const unsigned up00 = pkh(u0.x, u0.y), up01 = pkh(u0.z, u0.w);
                const unsigned up10 = pkh(u1.x, u1.y), up11 = pkh(u1.z, u1.w);
                float t0 = fd2(up00, vcp0[cc][0], fd2(up01, vcp0[cc][1], 0.f));
                t0 += __shfl_xor(t0, 1); t0 += __shfl_xor(t0, 2);
                float t1 = fd2(up10, vcp1[cc][0], fd2(up11, vcp1[cc][1], 0.f));
                t1 += __shfl_xor(t1, 1); t1 += __shfl_xor(t1, 2);
                wgt0[cc] = __expf(t0); s0 += wgt0[cc];
                wgt1[cc] = __expf(t1); s1 += wgt1[cc];
                uhp0[cc][0] = up00; uhp0[cc][1] = up01;
                uhp1[cc][0] = up10; uhp1[cc][1] = up11;
            }
            // exchange the 5-class exp-sums with the other c-group
            if (eq == 0) {
                xch[j & 1][cg][h][bl][0] = s0;
                xch[j & 1][cg][h][bl][1] = s1;
            }
            __syncthreads();
            const float i0 = 1.f / (s0 + xch[j & 1][cg ^ 1][h][bl][0]);
            const float i1 = 1.f / (s1 + xch[j & 1][cg ^ 1][h][bl][1]);
#pragma unroll
            for (int cc = 0; cc < 5; ++cc) {
                const float g0 = wgt0[cc] * i0, g1 = wgt1[cc] * i1;
                acc0[cc].x = fmaf(g0, hlo(uhp0[cc][0]), acc0[cc].x);
                acc0[cc].y = fmaf(g0, hhi(uhp0[cc][0]), acc0[cc].y);
                acc0[cc].z = fmaf(g0, hlo(uhp0[cc][1]), acc0[cc].z);
                acc0[cc].w = fmaf(g0, hhi(uhp0[cc][1]), acc0[cc].w);
                acc1[cc].x = fmaf(g1, hlo(uhp1[cc][0]), acc1[cc].x);
                acc1[cc].y = fmaf(g1, hhi(uhp1[cc][0]), acc1[cc].y);
                acc1[cc].z = fmaf(g1, hlo(uhp1[cc][1]), acc1[cc].z);
                acc1[cc].w = fmaf(g1, hhi(uhp1[cc][1]), acc1[cc].w);
            }
        }
    }

    // ---- direct fp16 partial store: partial[b][slot][c*8 + eq*2] ----
    const float fold = UNIFORM ? 0.1f : 1.f;   // softmax(0) = 1/10 folded out
#pragma unroll
    for (int cc = 0; cc < 5; ++cc) {
        const int c = cbase + cc;
        *(uint2*)(partial + ((size_t)b0 * NSLOT_ + blk) * PROW_ + c * 8 + eq * 2) =
            make_uint2(hpack(acc0[cc].x * fold, acc0[cc].y * fold),
                       hpack(acc0[cc].z * fold, acc0[cc].w * fold));
        *(uint2*)(partial + ((size_t)b1 * NSLOT_ + blk) * PROW_ + c * 8 + eq * 2) =
            make_uint2(hpack(acc1[cc].x * fold, acc1[cc].y * fold),
                       hpack(acc1[cc].z * fold, acc1[cc].w * fold));
    }
}

// Reduce stage A: 512 blocks = (b, sg); sum 128 slots -> sub[b][sg][160] f32.
__global__ __launch_bounds__(256) void caps_redA(
    const unsigned* __restrict__ partial, float* __restrict__ sub)
{
    const int b  = (int)blockIdx.x >> 3;
    const int sg = (int)blockIdx.x & 7;
    const int tid = (int)threadIdx.x;
    const int sc   = tid >> 5;          // 0..7
    const int col4 = tid & 31;          // active < 20
    __shared__ float red[8][20][8];
    if (col4 < 20) {
        float s[8];
#pragma unroll
        for (int p = 0; p < 8; ++p) s[p] = 0.f;
        const int slot0 = sg * (NSLOT_ / NSG_) + sc * 16;
        const uint4* base = (const uint4*)(partial +
            ((size_t)b * NSLOT_ + slot0) * PROW_) + col4;
#pragma unroll 4
        for (int k = 0; k < 16; ++k) {
            const uint4 q = base[k * (PROW_ / 4)];
            const float2 f0 = hunpack(q.x), f1 = hunpack(q.y);
            const float2 f2 = hunpack(q.z), f3 = hunpack(q.w);
            s[0] += f0.x; s[1] += f0.y; s[2] += f1.x; s[3] += f1.y;
            s[4] += f2.x; s[5] += f2.y; s[6] += f3.x; s[7] += f3.y;
        }
#pragma unroll
        for (int p = 0; p < 8; ++p) red[sc][col4][p] = s[p];
    }
    __syncthreads();
    if (tid < 160) {
        const int c4 = tid >> 3, p = tid & 7;
        float s = 0.f;
#pragma unroll
        for (int ch = 0; ch < 8; ++ch) s += red[ch][c4][p];
        sub[((size_t)b * NSG_ + sg) * (C_ * E_) + c4 * 8 + p] = s;
    }
}

// Reduce stage B: 64 blocks (one per b): sum 8 subpartials, squash, update.
__global__ __launch_bounds__(192) void caps_redB(
    const float* __restrict__ sub, float* __restrict__ v_cum,
    float* __restrict__ out, int mode)
{
    const int b = (int)blockIdx.x;
    const int tid = (int)threadIdx.x;
    if (tid >= C_ * E_) return;
    float s = 0.f;
#pragma unroll
    for (int sg = 0; sg < NSG_; ++sg)
        s += sub[((size_t)b * NSG_ + sg) * (C_ * E_) + tid];
    float p = s * s;                     // sum over the 16 e lanes of this c
    p += __shfl_xor(p, 1); p += __shfl_xor(p, 2);
    p += __shfl_xor(p, 4); p += __shfl_xor(p, 8);
    const float sc = (p / (1.f + p)) * rsqrtf(p + EPS_);
    const float v = sc * s;
    const int o = b * (C_ * E_) + tid;
    if (mode == 2)      out[o] = v;
    else if (mode == 0) v_cum[o] = v;
    else                v_cum[o] += v;
}

extern "C" void kernel_launch(void* const* d_in, const int* in_sizes, int n_in,
                              void* d_out, int out_size, void* d_ws, size_t ws_size,
                              hipStream_t stream) {
    const float* x = (const float*)d_in[0];
    const float* W = (const float*)d_in[1];
    float* out = (float*)d_out;

    // ws layout (R5 proved ws >= 42 MB):
    //   partial 20.97 MB | sub 327 KB | v_cum 40 KB | wpk 10.49 MB | xpk 4 MB
    char* p = (char*)d_ws;
    unsigned* partial = (unsigned*)p;
    p += (size_t)B_ * NSLOT_ * PROW_ * sizeof(unsigned);
    float* sub = (float*)p;
    p += (size_t)B_ * NSG_ * C_ * E_ * sizeof(float);
    float* v_cum = (float*)p;
    p += (size_t)B_ * C_ * E_ * sizeof(float);
    uint4* wpk = (uint4*)p;
    p += (size_t)NBLK_ * WG_ * sizeof(uint4);
    uint4* xpk = (uint4*)p;

    for (int t = 0; t < 3; ++t) {
        if (t == 0)
            caps_pass<true ><<<dim3(NBLK_), 256, 0, stream>>>(x, W, v_cum, partial, wpk, xpk);
        else
            caps_pass<false><<<dim3(NBLK_), 256, 0, stream>>>(x, W, v_cum, partial, wpk, xpk);
        caps_redA<<<dim3(B_ * NSG_), 256, 0, stream>>>(partial, sub);
        caps_redB<<<dim3(B_), 192, 0, stream>>>(sub, v_cum, out, t);
    }
}